// Round 4
// baseline (79018.011 us; speedup 1.0000x reference)
//
#include <hip/hip_runtime.h>

#define T_STEPS 16384
#define HID     1000
#define NB      250      // workgroups; each owns 4 hidden units (wave w <-> unit 4*bid+w)
#define NTH     256      // 4 waves
#define RS      1024     // LDS row stride: [W_hh(1000) | W_ih(18) | b(1) | 0 x5]
#define SPINL   65536    // flag-poll bound before permanent fallback to direct LLC poll

typedef unsigned int       uint32;
typedef unsigned long long u64;
typedef __attribute__((ext_vector_type(2))) u64 u64x2;

// d_ws layout (bytes):
//  [0, 32768)      entries: 2 parities x 16KB; parity p, WG b -> 64B line (8 u64), slot wv
//  [32768, 32800)  relay_ctr[8]
//  [33024, ...)    8 XCD blocks, stride 16512:
//                    parity0 region @0 (250 x 32B), parity1 region @8192, flag u32 @16384
#define ENT_PAR_U64 2048
#define CTR_OFF     32768
#define REG_OFF     33024
#define REG_PAR     8192
#define REG_FLAG    16384
#define REG_STRIDE  16512
#define WS_ZERO     (REG_OFF + 8 * REG_STRIDE)

__device__ __forceinline__ u64 ag_load(const u64* p) {
  return __hip_atomic_load(p, __ATOMIC_RELAXED, __HIP_MEMORY_SCOPE_AGENT);
}
__device__ __forceinline__ void ag_store(u64* p, u64 v) {
  __hip_atomic_store(p, v, __ATOMIC_RELAXED, __HIP_MEMORY_SCOPE_AGENT);
}
__device__ __forceinline__ u64 pack_entry(float v, uint32 seq) {
  return ((u64)seq << 32) | (u64)__float_as_uint(v);
}
// sc0-only (L1-bypass, local-L2-served) ops for the intra-XCD fast path
__device__ __forceinline__ uint32 flag_load(const uint32* p) {
  uint32 r;
  asm volatile("global_load_dword %0, %1, off sc0\n\ts_waitcnt vmcnt(0)"
               : "=v"(r) : "v"(p) : "memory");
  return r;
}
__device__ __forceinline__ void flag_store(uint32* p, uint32 v) {
  asm volatile("global_store_dword %0, %1, off sc0" :: "v"(p), "v"(v) : "memory");
}
__device__ __forceinline__ void l2_load_b256(const u64* p, u64x2& a, u64x2& b) {
  asm volatile("global_load_dwordx4 %0, %2, off sc0\n\t"
               "global_load_dwordx4 %1, %2, off offset:16 sc0\n\t"
               "s_waitcnt vmcnt(0)"
               : "=&v"(a), "=&v"(b) : "v"(p) : "memory");
}

// Direct LLC poll of one producer line (always correct; relays + fallback path).
// Terminates: an entry for target t can only be overwritten at publish t+2, which
// requires every WG (incl. the poller) to have finished consuming t.
__device__ __forceinline__ float4 poll_line(const u64* pb, uint32 tgt,
                                            u64* e_out /*4, may be null*/) {
  u64 e0, e1, e2, e3;
  for (;;) {
    e0 = ag_load(pb);     e1 = ag_load(pb + 1);
    e2 = ag_load(pb + 2); e3 = ag_load(pb + 3);
    if ((uint32)(e0 >> 32) == tgt && (uint32)(e1 >> 32) == tgt &&
        (uint32)(e2 >> 32) == tgt && (uint32)(e3 >> 32) == tgt) break;
  }
  if (e_out) { e_out[0] = e0; e_out[1] = e1; e_out[2] = e2; e_out[3] = e3; }
  float4 hv;
  hv.x = __uint_as_float((uint32)e0); hv.y = __uint_as_float((uint32)e1);
  hv.z = __uint_as_float((uint32)e2); hv.w = __uint_as_float((uint32)e3);
  return hv;
}

// Fill lds_v[0,1000) with target-tgt h (plus optional x tail), then sync.
// Relay: LLC poll -> region[tgt&1] -> flag.  Follower: flag (local L2) ->
// region[tgt&1] (local L2), seq-validated; bounded spin / mismatch -> LLC poll.
__device__ __forceinline__ void gather_step(
    const u64* ent_par, char* regbase, uint32* flagp,
    float* lds_v, int tid, bool is_relay, bool& fast_ok,
    uint32 tgt, bool relu, float xval, bool has_x)
{
  u64* regp = (u64*)(regbase + (tgt & 1) * REG_PAR);
  if (is_relay) {
    if (tid < NB) {
      u64 e[4];
      float4 hv = poll_line(ent_par + (size_t)tid * 8, tgt, e);
      volatile u64* rd = (volatile u64*)(regp + (size_t)tid * 4);  // 8B stores: no tearing
      rd[0] = e[0]; rd[1] = e[1]; rd[2] = e[2]; rd[3] = e[3];
      if (relu) { hv.x=fmaxf(hv.x,0.f); hv.y=fmaxf(hv.y,0.f);
                  hv.z=fmaxf(hv.z,0.f); hv.w=fmaxf(hv.w,0.f); }
      *(float4*)&lds_v[4 * tid] = hv;
    }
    if (has_x) lds_v[1000 + tid] = xval;
    asm volatile("s_waitcnt vmcnt(0)" ::: "memory");   // region stores acked in L2
    __syncthreads();
    if (tid == 0) flag_store(flagp, tgt);              // flag visible only after data
  } else {
    if (fast_ok) {
      int spins = 0;
      for (;;) {
        uint32 f = flag_load(flagp);
        if ((int)(f - tgt) >= 0) break;
        if (++spins >= SPINL) { fast_ok = false; break; }
      }
    }
    if (tid < NB) {
      float4 hv; bool got = false;
      if (fast_ok) {
        u64x2 a, b;
        l2_load_b256(regp + (size_t)tid * 4, a, b);
        if ((uint32)(a.x >> 32) == tgt && (uint32)(a.y >> 32) == tgt &&
            (uint32)(b.x >> 32) == tgt && (uint32)(b.y >> 32) == tgt) {
          hv.x = __uint_as_float((uint32)a.x); hv.y = __uint_as_float((uint32)a.y);
          hv.z = __uint_as_float((uint32)b.x); hv.w = __uint_as_float((uint32)b.y);
          got = true;
        }
      }
      if (!got) hv = poll_line(ent_par + (size_t)tid * 8, tgt, nullptr);
      if (relu) { hv.x=fmaxf(hv.x,0.f); hv.y=fmaxf(hv.y,0.f);
                  hv.z=fmaxf(hv.z,0.f); hv.w=fmaxf(hv.w,0.f); }
      *(float4*)&lds_v[4 * tid] = hv;
    }
    if (has_x) lds_v[1000 + tid] = xval;
    __syncthreads();
  }
}

__global__ __launch_bounds__(NTH) void lstm_mlp_kernel(
    const float* __restrict__ x,    const float* __restrict__ h0,
    const float* __restrict__ c0,   const float* __restrict__ W_ih,
    const float* __restrict__ W_hh, const float* __restrict__ b_ih,
    const float* __restrict__ b_hh,
    const float* __restrict__ W1, const float* __restrict__ b1,
    const float* __restrict__ W2, const float* __restrict__ b2,
    const float* __restrict__ W3, const float* __restrict__ b3,
    const float* __restrict__ W4, const float* __restrict__ b4,
    const float* __restrict__ Wo, const float* __restrict__ bo,
    char* __restrict__ wsb, float* __restrict__ out)
{
  __shared__ __align__(16) float lds_W[16 * RS];  // 64 KB: 16 LSTM gate rows
  __shared__ __align__(16) float lds_v[RS];       // [h(1000) | x(18) | 1.0 | 0 x5]
  __shared__ float lds_log[3];
  __shared__ uint32 lds_meta[2];                  // {xcc, is_relay}

  const int tid   = threadIdx.x;
  const int bid   = blockIdx.x;
  const int wv    = tid >> 6;
  const int lane  = tid & 63;
  const int lane4 = lane * 4;

  u64*    ent       = (u64*)wsb;
  uint32* relay_ctr = (uint32*)(wsb + CTR_OFF);

  // -------- election: first WG per physical XCD becomes that XCD's relay --------
  if (tid == 0) {
    uint32 xcc = (uint32)__builtin_amdgcn_s_getreg(20 | (3 << 11)) & 7u; // HW_REG_XCC_ID[3:0]
    lds_meta[0] = xcc;
    lds_meta[1] = (atomicAdd(&relay_ctr[xcc], 1u) == 0u) ? 1u : 0u;
  }

  // -------- stage 16 LSTM gate rows into LDS (W_hh read from HBM once) ----------
  for (int rr = 0; rr < 16; ++rr) {               // rr = w*4 + g
    const int w = rr >> 2, g = rr & 3;
    const int grow = g * HID + 4 * bid + w;
    const float* src = W_hh + (size_t)grow * HID;
    float* dst = lds_W + rr * RS;
    for (int k4 = tid; k4 < 250; k4 += NTH)
      *(float4*)&dst[k4 * 4] = *(const float4*)&src[k4 * 4];
    if (tid < 24) {
      float v = 0.f;
      if (tid < 18)       v = W_ih[(size_t)grow * 18 + tid];
      else if (tid == 18) v = b_ih[grow] + b_hh[grow];
      dst[1000 + tid] = v;
    }
  }
  if (tid < 24) lds_v[1000 + tid] = (tid == 18) ? 1.f : 0.f;

  float c_state = 0.f;
  if (lane == 0) c_state = c0[4 * bid + wv];
  __syncthreads();

  const uint32 xcc      = lds_meta[0];
  const bool   is_relay = lds_meta[1] != 0;
  char*   regbase = wsb + REG_OFF + (size_t)xcc * REG_STRIDE;
  uint32* flagp   = (uint32*)(regbase + REG_FLAG);
  bool fast_ok = true;

  // -------- 16384-step recurrence -----------------------------------------------
  for (int t = 1; t <= T_STEPS; ++t) {
    float xval = 0.f;
    if (tid < 18) xval = x[(size_t)(t - 1) * 18 + tid];   // issued before wait

    if (t == 1) {
      if (tid < NB) *(float4*)&lds_v[4 * tid] = *(const float4*)&h0[4 * tid];
      if (tid < 18) lds_v[1000 + tid] = xval;
      __syncthreads();
    } else {
      gather_step(ent + ((t - 1) & 1) * ENT_PAR_U64, regbase, flagp,
                  lds_v, tid, is_relay, fast_ok,
                  (uint32)(t - 1), false, xval, tid < 18);
    }

    // wave wv: 4 gate rows (i,f,g,o of its unit), full-wave dots, v reused
    float4 v0 = *(const float4*)&lds_v[lane4];
    float4 v1 = *(const float4*)&lds_v[256 + lane4];
    float4 v2 = *(const float4*)&lds_v[512 + lane4];
    float4 v3 = *(const float4*)&lds_v[768 + lane4];
    float acc[4];
#pragma unroll
    for (int g = 0; g < 4; ++g) {
      const float* wr = lds_W + (wv * 4 + g) * RS + lane4;
      float4 w0 = *(const float4*)(wr);
      float4 w1 = *(const float4*)(wr + 256);
      float4 w2 = *(const float4*)(wr + 512);
      float4 w3 = *(const float4*)(wr + 768);
      float s;
      s = w0.x * v0.x;         s = fmaf(w0.y, v0.y, s);
      s = fmaf(w0.z, v0.z, s); s = fmaf(w0.w, v0.w, s);
      s = fmaf(w1.x, v1.x, s); s = fmaf(w1.y, v1.y, s);
      s = fmaf(w1.z, v1.z, s); s = fmaf(w1.w, v1.w, s);
      s = fmaf(w2.x, v2.x, s); s = fmaf(w2.y, v2.y, s);
      s = fmaf(w2.z, v2.z, s); s = fmaf(w2.w, v2.w, s);
      s = fmaf(w3.x, v3.x, s); s = fmaf(w3.y, v3.y, s);
      s = fmaf(w3.z, v3.z, s); s = fmaf(w3.w, v3.w, s);
      acc[g] = s;
    }
#pragma unroll
    for (int g = 0; g < 4; ++g) {
      acc[g] += __shfl_xor(acc[g], 1);
      acc[g] += __shfl_xor(acc[g], 2);
    }
    const int sel = lane & 3;
    float s = (sel == 0) ? acc[0] : (sel == 1) ? acc[1] : (sel == 2) ? acc[2] : acc[3];
    s += __shfl_xor(s, 4);  s += __shfl_xor(s, 8);
    s += __shfl_xor(s, 16); s += __shfl_xor(s, 32);

    float pre = (sel == 2) ? 2.f * s : s;
    float sg  = 1.f / (1.f + __expf(-pre));
    float act = (sel == 2) ? (2.f * sg - 1.f) : sg;   // tanh(s) = 2*sig(2s)-1
    float a_i = __shfl(act, 0);
    float a_f = __shfl(act, 1);
    float a_g = __shfl(act, 2);
    float a_o = __shfl(act, 3);

    if (lane == 0) {
      c_state  = fmaf(a_f, c_state, a_i * a_g);
      float ac = fabsf(c_state);
      float e  = __expf(-2.f * ac);                   // overflow-safe tanh
      float th = (1.f - e) / (1.f + e);
      th = copysignf(th, c_state);
      float hv = a_o * th;
      ag_store(ent + (t & 1) * ENT_PAR_U64 + (size_t)bid * 8 + wv,
               pack_entry(hv, (uint32)t));
    }
    __syncthreads();   // protect lds_v against next step's overwrite
  }

  // -------- MLP: 4 rounds, wave wv computes unit 4*bid+wv -----------------------
  for (int r = 1; r <= 4; ++r) {
    const uint32 sprev = (uint32)(T_STEPS + r - 1);
    gather_step(ent + (sprev & 1) * ENT_PAR_U64, regbase, flagp,
                lds_v, tid, is_relay, fast_ok, sprev, (r == 1), 0.f, false);

    const float* WL  = (r == 1) ? W1 : (r == 2) ? W2 : (r == 3) ? W3 : W4;
    const float* bLp = (r == 1) ? b1 : (r == 2) ? b2 : (r == 3) ? b3 : b4;
    const int u = 4 * bid + wv;
    const float* row = WL + (size_t)u * HID;

    float4 v0 = *(const float4*)&lds_v[lane4];
    float4 v1 = *(const float4*)&lds_v[256 + lane4];
    float4 v2 = *(const float4*)&lds_v[512 + lane4];
    float4 v3 = *(const float4*)&lds_v[768 + lane4];
    float4 w0 = *(const float4*)(row + lane4);
    float4 w1 = *(const float4*)(row + 256 + lane4);
    float4 w2 = *(const float4*)(row + 512 + lane4);
    float4 w3 = {0.f, 0.f, 0.f, 0.f};
    if (lane < 58) w3 = *(const float4*)(row + 768 + lane4);  // floats [768,1000)

    float s;
    s = w0.x * v0.x;         s = fmaf(w0.y, v0.y, s);
    s = fmaf(w0.z, v0.z, s); s = fmaf(w0.w, v0.w, s);
    s = fmaf(w1.x, v1.x, s); s = fmaf(w1.y, v1.y, s);
    s = fmaf(w1.z, v1.z, s); s = fmaf(w1.w, v1.w, s);
    s = fmaf(w2.x, v2.x, s); s = fmaf(w2.y, v2.y, s);
    s = fmaf(w2.z, v2.z, s); s = fmaf(w2.w, v2.w, s);
    s = fmaf(w3.x, v3.x, s); s = fmaf(w3.y, v3.y, s);
    s = fmaf(w3.z, v3.z, s); s = fmaf(w3.w, v3.w, s);
    s += __shfl_xor(s, 1);  s += __shfl_xor(s, 2);  s += __shfl_xor(s, 4);
    s += __shfl_xor(s, 8);  s += __shfl_xor(s, 16); s += __shfl_xor(s, 32);

    if (lane == 0) {
      float y = fmaxf(s + bLp[u], 0.f);
      ag_store(ent + ((T_STEPS + r) & 1) * ENT_PAR_U64 + (size_t)bid * 8 + wv,
               pack_entry(y, (uint32)(T_STEPS + r)));
    }
    __syncthreads();
  }

  // -------- final relay round + WG0 logits/softmax ------------------------------
  const uint32 sfin = (uint32)(T_STEPS + 4);
  if (is_relay || bid == 0) {
    gather_step(ent + (sfin & 1) * ENT_PAR_U64, regbase, flagp,
                lds_v, tid, is_relay, fast_ok, sfin, false, 0.f, false);
  }
  if (bid == 0) {
    float s = 0.f;
    if (wv < 3) {
      const float* row = Wo + (size_t)wv * HID;
      float4 v0 = *(const float4*)&lds_v[lane4];
      float4 v1 = *(const float4*)&lds_v[256 + lane4];
      float4 v2 = *(const float4*)&lds_v[512 + lane4];
      float4 v3 = *(const float4*)&lds_v[768 + lane4];
      float4 w0 = *(const float4*)(row + lane4);
      float4 w1 = *(const float4*)(row + 256 + lane4);
      float4 w2 = *(const float4*)(row + 512 + lane4);
      float4 w3 = {0.f, 0.f, 0.f, 0.f};
      if (lane < 58) w3 = *(const float4*)(row + 768 + lane4);
      s = w0.x * v0.x;         s = fmaf(w0.y, v0.y, s);
      s = fmaf(w0.z, v0.z, s); s = fmaf(w0.w, v0.w, s);
      s = fmaf(w1.x, v1.x, s); s = fmaf(w1.y, v1.y, s);
      s = fmaf(w1.z, v1.z, s); s = fmaf(w1.w, v1.w, s);
      s = fmaf(w2.x, v2.x, s); s = fmaf(w2.y, v2.y, s);
      s = fmaf(w2.z, v2.z, s); s = fmaf(w2.w, v2.w, s);
      s = fmaf(w3.x, v3.x, s); s = fmaf(w3.z, v3.z, s);
      s = fmaf(w3.y, v3.y, s); s = fmaf(w3.w, v3.w, s);
      s += __shfl_xor(s, 1);  s += __shfl_xor(s, 2);  s += __shfl_xor(s, 4);
      s += __shfl_xor(s, 8);  s += __shfl_xor(s, 16); s += __shfl_xor(s, 32);
    }
    if (wv < 3 && lane == 0) lds_log[wv] = s + bo[wv];
    __syncthreads();
    if (tid == 0) {
      float l0 = lds_log[0], l1 = lds_log[1], l2 = lds_log[2];
      float m  = fmaxf(l0, fmaxf(l1, l2));
      float e0 = __expf(l0 - m), e1 = __expf(l1 - m), e2 = __expf(l2 - m);
      float inv = 1.f / (e0 + e1 + e2);
      out[0] = e0 * inv; out[1] = e1 * inv; out[2] = e2 * inv;
    }
  }
}

extern "C" void kernel_launch(void* const* d_in, const int* in_sizes, int n_in,
                              void* d_out, int out_size, void* d_ws, size_t ws_size,
                              hipStream_t stream) {
  const float* x    = (const float*)d_in[0];
  const float* h0   = (const float*)d_in[1];
  const float* c0   = (const float*)d_in[2];
  const float* W_ih = (const float*)d_in[3];
  const float* W_hh = (const float*)d_in[4];
  const float* b_ih = (const float*)d_in[5];
  const float* b_hh = (const float*)d_in[6];
  const float* W1 = (const float*)d_in[7];
  const float* b1 = (const float*)d_in[8];
  const float* W2 = (const float*)d_in[9];
  const float* b2 = (const float*)d_in[10];
  const float* W3 = (const float*)d_in[11];
  const float* b3 = (const float*)d_in[12];
  const float* W4 = (const float*)d_in[13];
  const float* b4 = (const float*)d_in[14];
  const float* Wo = (const float*)d_in[15];
  const float* bo = (const float*)d_in[16];

  char* wsb = (char*)d_ws;
  // entries + relay_ctr + regions must be zeroed EVERY launch (seqs repeat across replays;
  // dispatch-boundary release/acquire makes this memset globally visible to the kernel)
  hipMemsetAsync(wsb, 0, WS_ZERO, stream);

  // +16KB dynamic LDS: static ~70KB -> ~86KB, forces 1 WG/CU (250 WGs all resident)
  hipLaunchKernelGGL(lstm_mlp_kernel, dim3(NB), dim3(NTH), 16384, stream,
                     x, h0, c0, W_ih, W_hh, b_ih, b_hh,
                     W1, b1, W2, b2, W3, b3, W4, b4, Wo, bo,
                     wsb, (float*)d_out);
}

// Round 5
// 51754.816 us; speedup vs baseline: 1.5268x; 1.5268x over previous
//
#include <hip/hip_runtime.h>

#define T_STEPS 16384
#define HID     1000
#define NB      250      // workgroups; each owns 4 hidden units (wave w <-> unit 4*bid+w)
#define NTH     256      // 4 waves
#define RS      1024     // LDS row stride: [W_hh(1000) | W_ih(18) | b(1) | 0 x5]
#define EPAR    1024     // u64 entries per parity buffer (1000 used, padded to line mult)

typedef unsigned int       uint32;
typedef unsigned long long u64;

__device__ __forceinline__ u64 ag_load(const u64* p) {
  return __hip_atomic_load(p, __ATOMIC_RELAXED, __HIP_MEMORY_SCOPE_AGENT);
}
__device__ __forceinline__ void ag_store(u64* p, u64 v) {
  __hip_atomic_store(p, v, __ATOMIC_RELAXED, __HIP_MEMORY_SCOPE_AGENT);
}
__device__ __forceinline__ u64 pack_entry(float v, uint32 seq) {
  return ((u64)seq << 32) | (u64)__float_as_uint(v);
}

// Dense-entry gather: entries ep[0..999] are {val lo32, seq hi32}, 8B stride.
// Thread tid polls entries {tid, tid+256, tid+512, tid+768} -> one wave instr
// covers 64 consecutive entries = 8 cachelines = 8 requests (vs 64 uncoalesced).
// Per-entry done bits: validated entries stop generating traffic. Terminates:
// entry seq==tgt can only be overwritten at tgt+2, which requires this WG to
// have consumed tgt first (2-parity argument).
__device__ __forceinline__ void gather_dense(const u64* ep, uint32 tgt, int tid,
                                             float* lds_v, bool relu) {
  uint32 pend = (768 + tid < HID) ? 0xFu : 0x7u;   // entry idx >= 1000: never polled
  do {
    u64 e0 = 0, e1 = 0, e2 = 0, e3 = 0;
    if (pend & 1u) e0 = ag_load(ep + tid);
    if (pend & 2u) e1 = ag_load(ep + 256 + tid);
    if (pend & 4u) e2 = ag_load(ep + 512 + tid);
    if (pend & 8u) e3 = ag_load(ep + 768 + tid);
    uint32 got = 0;
    if ((pend & 1u) && (uint32)(e0 >> 32) == tgt) {
      float v = __uint_as_float((uint32)e0);
      lds_v[tid] = relu ? fmaxf(v, 0.f) : v;  got |= 1u;
    }
    if ((pend & 2u) && (uint32)(e1 >> 32) == tgt) {
      float v = __uint_as_float((uint32)e1);
      lds_v[256 + tid] = relu ? fmaxf(v, 0.f) : v;  got |= 2u;
    }
    if ((pend & 4u) && (uint32)(e2 >> 32) == tgt) {
      float v = __uint_as_float((uint32)e2);
      lds_v[512 + tid] = relu ? fmaxf(v, 0.f) : v;  got |= 4u;
    }
    if ((pend & 8u) && (uint32)(e3 >> 32) == tgt) {
      float v = __uint_as_float((uint32)e3);
      lds_v[768 + tid] = relu ? fmaxf(v, 0.f) : v;  got |= 8u;
    }
    pend &= ~got;
  } while (pend);
}

__global__ __launch_bounds__(NTH) void lstm_mlp_kernel(
    const float* __restrict__ x,    const float* __restrict__ h0,
    const float* __restrict__ c0,   const float* __restrict__ W_ih,
    const float* __restrict__ W_hh, const float* __restrict__ b_ih,
    const float* __restrict__ b_hh,
    const float* __restrict__ W1, const float* __restrict__ b1,
    const float* __restrict__ W2, const float* __restrict__ b2,
    const float* __restrict__ W3, const float* __restrict__ b3,
    const float* __restrict__ W4, const float* __restrict__ b4,
    const float* __restrict__ Wo, const float* __restrict__ bo,
    u64* __restrict__ ent, float* __restrict__ out)
{
  __shared__ __align__(16) float lds_W[16 * RS];  // 64 KB: 16 LSTM gate rows
  __shared__ __align__(16) float lds_v[RS];       // [h(1000) | x(18) | 1.0 | 0 x5]
  __shared__ float lds_log[3];

  const int tid   = threadIdx.x;
  const int bid   = blockIdx.x;
  const int wv    = tid >> 6;     // wave 0..3 <-> hidden unit 4*bid+wv
  const int lane  = tid & 63;
  const int lane4 = lane * 4;

  // -------- stage 16 LSTM gate rows into LDS (W_hh read from HBM once) ----------
  for (int rr = 0; rr < 16; ++rr) {               // rr = w*4 + g
    const int w = rr >> 2, g = rr & 3;
    const int grow = g * HID + 4 * bid + w;       // global gate row in [0,4000)
    const float* src = W_hh + (size_t)grow * HID;
    float* dst = lds_W + rr * RS;
    for (int k4 = tid; k4 < 250; k4 += NTH)
      *(float4*)&dst[k4 * 4] = *(const float4*)&src[k4 * 4];
    if (tid < 24) {                               // tail [1000,1024)
      float v = 0.f;
      if (tid < 18)       v = W_ih[(size_t)grow * 18 + tid];
      else if (tid == 18) v = b_ih[grow] + b_hh[grow];
      dst[1000 + tid] = v;
    }
  }
  if (tid < 24) lds_v[1000 + tid] = (tid == 18) ? 1.f : 0.f;  // bias-one + zero pad

  float c_state = 0.f;
  if (lane == 0) c_state = c0[4 * bid + wv];
  __syncthreads();

  // -------- 16384-step recurrence ------------------------------------------------
  for (int t = 1; t <= T_STEPS; ++t) {
    float xval = 0.f;
    const bool hx = (tid < 18);
    if (hx) xval = x[(size_t)(t - 1) * 18 + tid];   // independent: issues before poll

    if (t == 1) {
      if (tid < NB) *(float4*)&lds_v[4 * tid] = *(const float4*)&h0[4 * tid];
    } else {
      gather_dense(ent + ((t - 1) & 1) * EPAR, (uint32)(t - 1), tid, lds_v, false);
    }
    if (hx) lds_v[1000 + tid] = xval;
    __syncthreads();

    // wave wv: 4 gate rows (i,f,g,o of its unit), full-wave dots, v reused
    float4 v0 = *(const float4*)&lds_v[lane4];
    float4 v1 = *(const float4*)&lds_v[256 + lane4];
    float4 v2 = *(const float4*)&lds_v[512 + lane4];
    float4 v3 = *(const float4*)&lds_v[768 + lane4];
    float acc[4];
#pragma unroll
    for (int g = 0; g < 4; ++g) {
      const float* wr = lds_W + (wv * 4 + g) * RS + lane4;
      float4 w0 = *(const float4*)(wr);
      float4 w1 = *(const float4*)(wr + 256);
      float4 w2 = *(const float4*)(wr + 512);
      float4 w3 = *(const float4*)(wr + 768);
      float s;
      s = w0.x * v0.x;         s = fmaf(w0.y, v0.y, s);
      s = fmaf(w0.z, v0.z, s); s = fmaf(w0.w, v0.w, s);
      s = fmaf(w1.x, v1.x, s); s = fmaf(w1.y, v1.y, s);
      s = fmaf(w1.z, v1.z, s); s = fmaf(w1.w, v1.w, s);
      s = fmaf(w2.x, v2.x, s); s = fmaf(w2.y, v2.y, s);
      s = fmaf(w2.z, v2.z, s); s = fmaf(w2.w, v2.w, s);
      s = fmaf(w3.x, v3.x, s); s = fmaf(w3.y, v3.y, s);
      s = fmaf(w3.z, v3.z, s); s = fmaf(w3.w, v3.w, s);
      acc[g] = s;
    }
#pragma unroll
    for (int g = 0; g < 4; ++g) {
      acc[g] += __shfl_xor(acc[g], 1);
      acc[g] += __shfl_xor(acc[g], 2);
    }
    const int sel = lane & 3;
    float s = (sel == 0) ? acc[0] : (sel == 1) ? acc[1] : (sel == 2) ? acc[2] : acc[3];
    s += __shfl_xor(s, 4);  s += __shfl_xor(s, 8);
    s += __shfl_xor(s, 16); s += __shfl_xor(s, 32);

    float pre = (sel == 2) ? 2.f * s : s;
    float sg  = 1.f / (1.f + __expf(-pre));
    float act = (sel == 2) ? (2.f * sg - 1.f) : sg;   // tanh(s) = 2*sig(2s)-1
    float a_i = __shfl(act, 0);
    float a_f = __shfl(act, 1);
    float a_g = __shfl(act, 2);
    float a_o = __shfl(act, 3);

    if (lane == 0) {
      c_state  = fmaf(a_f, c_state, a_i * a_g);
      float ac = fabsf(c_state);
      float e  = __expf(-2.f * ac);                   // overflow-safe tanh
      float th = (1.f - e) / (1.f + e);
      th = copysignf(th, c_state);
      float hv = a_o * th;
      ag_store(ent + (t & 1) * EPAR + (size_t)(4 * bid + wv),
               pack_entry(hv, (uint32)t));
    }
    __syncthreads();   // all waves done reading lds_v before next gather overwrites
  }

  // -------- MLP: 4 rounds, wave wv computes unit 4*bid+wv -----------------------
  for (int r = 1; r <= 4; ++r) {
    const uint32 sprev = (uint32)(T_STEPS + r - 1);
    gather_dense(ent + (sprev & 1) * EPAR, sprev, tid, lds_v, /*relu h_T*/ (r == 1));
    __syncthreads();

    const float* WL  = (r == 1) ? W1 : (r == 2) ? W2 : (r == 3) ? W3 : W4;
    const float* bLp = (r == 1) ? b1 : (r == 2) ? b2 : (r == 3) ? b3 : b4;
    const int u = 4 * bid + wv;
    const float* row = WL + (size_t)u * HID;

    float4 v0 = *(const float4*)&lds_v[lane4];
    float4 v1 = *(const float4*)&lds_v[256 + lane4];
    float4 v2 = *(const float4*)&lds_v[512 + lane4];
    float4 v3 = *(const float4*)&lds_v[768 + lane4];
    float4 w0 = *(const float4*)(row + lane4);
    float4 w1 = *(const float4*)(row + 256 + lane4);
    float4 w2 = *(const float4*)(row + 512 + lane4);
    float4 w3 = {0.f, 0.f, 0.f, 0.f};
    if (lane < 58) w3 = *(const float4*)(row + 768 + lane4);  // floats [768,1000)

    float s;
    s = w0.x * v0.x;         s = fmaf(w0.y, v0.y, s);
    s = fmaf(w0.z, v0.z, s); s = fmaf(w0.w, v0.w, s);
    s = fmaf(w1.x, v1.x, s); s = fmaf(w1.y, v1.y, s);
    s = fmaf(w1.z, v1.z, s); s = fmaf(w1.w, v1.w, s);
    s = fmaf(w2.x, v2.x, s); s = fmaf(w2.y, v2.y, s);
    s = fmaf(w2.z, v2.z, s); s = fmaf(w2.w, v2.w, s);
    s = fmaf(w3.x, v3.x, s); s = fmaf(w3.y, v3.y, s);
    s = fmaf(w3.z, v3.z, s); s = fmaf(w3.w, v3.w, s);
    s += __shfl_xor(s, 1);  s += __shfl_xor(s, 2);  s += __shfl_xor(s, 4);
    s += __shfl_xor(s, 8);  s += __shfl_xor(s, 16); s += __shfl_xor(s, 32);

    if (lane == 0) {
      float y = fmaxf(s + bLp[u], 0.f);
      ag_store(ent + ((T_STEPS + r) & 1) * EPAR + (size_t)u,
               pack_entry(y, (uint32)(T_STEPS + r)));
    }
    __syncthreads();
  }

  // -------- final: WG0 computes logits + softmax --------------------------------
  if (bid == 0) {
    const uint32 sfin = (uint32)(T_STEPS + 4);
    gather_dense(ent + (sfin & 1) * EPAR, sfin, tid, lds_v, false);
    __syncthreads();

    float s = 0.f;
    if (wv < 3) {
      const float* row = Wo + (size_t)wv * HID;
      float4 v0 = *(const float4*)&lds_v[lane4];
      float4 v1 = *(const float4*)&lds_v[256 + lane4];
      float4 v2 = *(const float4*)&lds_v[512 + lane4];
      float4 v3 = *(const float4*)&lds_v[768 + lane4];
      float4 w0 = *(const float4*)(row + lane4);
      float4 w1 = *(const float4*)(row + 256 + lane4);
      float4 w2 = *(const float4*)(row + 512 + lane4);
      float4 w3 = {0.f, 0.f, 0.f, 0.f};
      if (lane < 58) w3 = *(const float4*)(row + 768 + lane4);
      s = w0.x * v0.x;         s = fmaf(w0.y, v0.y, s);
      s = fmaf(w0.z, v0.z, s); s = fmaf(w0.w, v0.w, s);
      s = fmaf(w1.x, v1.x, s); s = fmaf(w1.y, v1.y, s);
      s = fmaf(w1.z, v1.z, s); s = fmaf(w1.w, v1.w, s);
      s = fmaf(w2.x, v2.x, s); s = fmaf(w2.y, v2.y, s);
      s = fmaf(w2.z, v2.z, s); s = fmaf(w2.w, v2.w, s);
      s = fmaf(w3.x, v3.x, s); s = fmaf(w3.y, v3.y, s);
      s = fmaf(w3.z, v3.z, s); s = fmaf(w3.w, v3.w, s);
      s += __shfl_xor(s, 1);  s += __shfl_xor(s, 2);  s += __shfl_xor(s, 4);
      s += __shfl_xor(s, 8);  s += __shfl_xor(s, 16); s += __shfl_xor(s, 32);
    }
    if (wv < 3 && lane == 0) lds_log[wv] = s + bo[wv];
    __syncthreads();
    if (tid == 0) {
      float l0 = lds_log[0], l1 = lds_log[1], l2 = lds_log[2];
      float m  = fmaxf(l0, fmaxf(l1, l2));
      float e0 = __expf(l0 - m), e1 = __expf(l1 - m), e2 = __expf(l2 - m);
      float inv = 1.f / (e0 + e1 + e2);
      out[0] = e0 * inv; out[1] = e1 * inv; out[2] = e2 * inv;
    }
  }
}

extern "C" void kernel_launch(void* const* d_in, const int* in_sizes, int n_in,
                              void* d_out, int out_size, void* d_ws, size_t ws_size,
                              hipStream_t stream) {
  const float* x    = (const float*)d_in[0];
  const float* h0   = (const float*)d_in[1];
  const float* c0   = (const float*)d_in[2];
  const float* W_ih = (const float*)d_in[3];
  const float* W_hh = (const float*)d_in[4];
  const float* b_ih = (const float*)d_in[5];
  const float* b_hh = (const float*)d_in[6];
  const float* W1 = (const float*)d_in[7];
  const float* b1 = (const float*)d_in[8];
  const float* W2 = (const float*)d_in[9];
  const float* b2 = (const float*)d_in[10];
  const float* W3 = (const float*)d_in[11];
  const float* b3 = (const float*)d_in[12];
  const float* W4 = (const float*)d_in[13];
  const float* b4 = (const float*)d_in[14];
  const float* Wo = (const float*)d_in[15];
  const float* bo = (const float*)d_in[16];

  u64* ent = (u64*)d_ws;   // dense: 2 parities x 1024 u64 {val lo32, seq hi32}

  // seqs must start at 0 every launch (graph replays reuse the same workspace)
  hipMemsetAsync(ent, 0, 2 * EPAR * sizeof(u64), stream);

  // +16KB dynamic LDS: static ~68KB -> ~84KB total, forces 1 WG/CU (250 WGs spread)
  hipLaunchKernelGGL(lstm_mlp_kernel, dim3(NB), dim3(NTH), 16384, stream,
                     x, h0, c0, W_ih, W_hh, b_ih, b_hh,
                     W1, b1, W2, b2, W3, b3, W4, b4, Wo, bo,
                     ent, (float*)d_out);
}